// Round 11
// baseline (550.727 us; speedup 1.0000x reference)
//
#include <hip/hip_runtime.h>
#include <hip/hip_bf16.h>
#include <math.h>

// ---------------------------------------------------------------------------
// Round 24: R21 swizzles restored + 2-blocks/CU fused FFN + epilogue fix.
// R23 isolated R22's regression to the swizzle changes themselves (conflicts
// 14.2->10.9M but time 196->216): revert to R21's 3-bit XOR everywhere.
// Finding 1: fused-FFN epilogue had Cs[.][136] indexed with nl0<256 ->
// flat-index aliasing, ~half of x updates clobbered (absmax 0.25->0.64 at
// R18). Fixed with stride-264 staging.
// Finding 2: gemm_ffn per-slab ~10.5k cycles vs ~2k accounted -> serialized
// 3-barrier chain with ONE block/CU (160KB) and nothing to overlap. Fix:
// 64-row M-tile, 256 thr, single-buffered slab (A 16K | W1/h 32K | W2 32K
// = 80KB) -> 2 independent blocks/CU; cross-block TLP covers the bubbles.
// ---------------------------------------------------------------------------

using bf16 = __hip_bfloat16;
typedef __attribute__((ext_vector_type(4))) float f32x4;
typedef __attribute__((ext_vector_type(16))) float f32x16;
typedef long long i64;
typedef unsigned char uchar;

static __device__ __forceinline__ float wave_sum64(float v){
  #pragma unroll
  for (int o = 32; o >= 1; o >>= 1) v += __shfl_xor(v, o, 64);
  return v;
}

static __device__ __forceinline__ void gl_lds16(const void* g, void* l){
  __builtin_amdgcn_global_load_lds((const __attribute__((address_space(1))) void*)g,
                                   (__attribute__((address_space(3))) void*)l, 16, 0, 0);
}

// barrier that orders LDS ops only -- leaves vmcnt (prefetch) in flight.
static __device__ __forceinline__ void barrier_lgkm(){
  asm volatile("s_waitcnt lgkmcnt(0)" ::: "memory");
  __builtin_amdgcn_s_barrier();
}

static __device__ __forceinline__ unsigned pack2(float a, float b){
  union { bf16 h[2]; unsigned u; } u;
  u.h[0] = __float2bfloat16(a); u.h[1] = __float2bfloat16(b);
  return u.u;
}

static __device__ __forceinline__ uchar f2f8(float v){
  return (uchar)(__builtin_amdgcn_cvt_pk_fp8_f32(v, 0.f, 0, false) & 0xff);
}
static __device__ __forceinline__ unsigned pack4_fp8(float a, float b, float c, float d){
  int v = __builtin_amdgcn_cvt_pk_fp8_f32(a, b, 0, false);
  v = __builtin_amdgcn_cvt_pk_fp8_f32(c, d, v, true);
  return (unsigned)v;
}

// 2^x in one instruction (non-volatile: dead results get DCE'd).
static __device__ __forceinline__ float fexp2(float x){
  float r;
  asm("v_exp_f32 %0, %1" : "=v"(r) : "v"(x));
  return r;
}

// merged weight prep: all 6 jobs fp8 transposed. 1280 blocks.
__global__ __launch_bounds__(256) void cvt_all(
    const float* s0, const float* s1, const float* s2, const float* s3,
    const float* s4, const float* s5,
    uchar* d0, uchar* d1, uchar* d2, uchar* d3, uchar* d4, uchar* d5)
{
  __shared__ float t[32][33];
  const float* srcs[6] = {s0, s1, s2, s3, s4, s5};
  uchar* dsts[6] = {d0, d1, d2, d3, d4, d5};
  const int Ks[6] = {256, 256, 256, 256, 256, 2048};
  const int Ns[6] = {256, 256, 256, 256, 2048, 256};
  const int offs[7] = {0, 64, 128, 192, 256, 768, 1280};
  int bid = blockIdx.x, j = 5;
  #pragma unroll
  for (int q = 4; q >= 0; q--) if (bid < offs[q + 1]) j = q;
  int local = bid - offs[j];
  int K = Ks[j], N = Ns[j];
  const float* src = srcs[j];
  uchar* dst = dsts[j];
  int kt = K >> 5;
  int kb = (local % kt) * 32, nb = (local / kt) * 32;
  int tx = threadIdx.x & 31, ty = threadIdx.x >> 5;
  #pragma unroll
  for (int dy = 0; dy < 32; dy += 8)
    t[ty + dy][tx] = src[(size_t)(kb + ty + dy) * N + nb + tx];
  __syncthreads();
  #pragma unroll
  for (int dy = 0; dy < 32; dy += 8)
    dst[(size_t)(nb + ty + dy) * K + kb + tx] = f2f8(t[tx][ty + dy]);
}

// embed + PE + scale -> x (bf16), LN1 -> fp8 xn8. one wave/row, grid 23040.
__global__ __launch_bounds__(256) void embed_ln1(
    const int* __restrict__ src, const float* __restrict__ emb,
    const float* __restrict__ na, const float* __restrict__ nb,
    bf16* __restrict__ x, uchar* __restrict__ xn8)
{
  int row  = blockIdx.x * 4 + (threadIdx.x >> 6);
  int lane = threadIdx.x & 63;
  int s = row % 360;
  int tok = src[row];
  float4 v = *(const float4*)(emb + (size_t)tok * 256 + lane * 4);
  float vv[4] = {v.x, v.y, v.z, v.w};
  if (s < 340){
    const float C = (-2.0f / 256.0f) * 13.287712379549449f;
    #pragma unroll
    for (int t = 0; t < 4; t++){
      int c = lane * 4 + t;
      float ang = (float)s * exp2f(C * (float)c);
      float pe = (c & 1) ? cosf(ang) : sinf(ang);
      vv[t] = 16.0f * vv[t] + pe;
    }
  }
  float sum = wave_sum64(vv[0] + vv[1] + vv[2] + vv[3]);
  float mu = sum * (1.0f / 256.0f);
  float d0 = vv[0]-mu, d1 = vv[1]-mu, d2 = vv[2]-mu, d3 = vv[3]-mu;
  float sq = wave_sum64(d0*d0 + d1*d1 + d2*d2 + d3*d3);
  float inv = 1.0f / (sqrtf(sq * (1.0f / 255.0f)) + 1e-6f);
  bf16 xo[4] = { __float2bfloat16(vv[0]), __float2bfloat16(vv[1]),
                 __float2bfloat16(vv[2]), __float2bfloat16(vv[3]) };
  *(uint2*)(x + (size_t)row * 256 + lane * 4) = *(uint2*)xo;
  float4 a4 = *(const float4*)(na + lane * 4);
  float4 b4 = *(const float4*)(nb + lane * 4);
  unsigned u = pack4_fp8(a4.x * d0 * inv + b4.x, a4.y * d1 * inv + b4.y,
                         a4.z * d2 * inv + b4.z, a4.w * d3 * inv + b4.w);
  *(unsigned*)(xn8 + (size_t)row * 256 + lane * 4) = u;
}

// LN2 over bf16 x -> fp8 xn8. one wave per row. grid 23040.
__global__ __launch_bounds__(256) void ln_k8(
    const bf16* __restrict__ x, const float* __restrict__ na,
    const float* __restrict__ nb, uchar* __restrict__ xn8)
{
  int row  = blockIdx.x * 4 + (threadIdx.x >> 6);
  int lane = threadIdx.x & 63;
  uint2 raw = *(const uint2*)(x + (size_t)row * 256 + lane * 4);
  bf16* xr = (bf16*)&raw;
  float v0 = __bfloat162float(xr[0]), v1 = __bfloat162float(xr[1]);
  float v2 = __bfloat162float(xr[2]), v3 = __bfloat162float(xr[3]);
  float sum = wave_sum64(v0 + v1 + v2 + v3);
  float mu = sum * (1.0f / 256.0f);
  float d0 = v0-mu, d1 = v1-mu, d2 = v2-mu, d3 = v3-mu;
  float sq = wave_sum64(d0*d0 + d1*d1 + d2*d2 + d3*d3);
  float inv = 1.0f / (sqrtf(sq * (1.0f / 255.0f)) + 1e-6f);
  float4 a4 = *(const float4*)(na + lane * 4);
  float4 b4 = *(const float4*)(nb + lane * 4);
  unsigned u = pack4_fp8(a4.x * d0 * inv + b4.x, a4.y * d1 * inv + b4.y,
                         a4.z * d2 * inv + b4.z, a4.w * d3 * inv + b4.w);
  *(unsigned*)(xn8 + (size_t)row * 256 + lane * 4) = u;
}

// ---------------------------------------------------------------------------
// K-resident fp8 GEMM (K=256 fixed): C = A[M][256] @ Bt[N][256]^T.
// 128x128 tile, full K in LDS (As+Bs=64KB), ONE barrier, 32x32x16 MFMA.
// R21 chunk swizzle: stored[row][p] = logical[row][(p&8)|((p&7)^(row&7))].
// MODE 3: bf16 residual in-place += acc (+bias) (swapped)
// MODE 4: QK (N=512): region n0>>8: 0 q8-layout, 1 k8-layout (swapped)
// MODE 5: V  (N=256): v^T8 layout [bh][64][360]  (unswapped)
// ---------------------------------------------------------------------------
template<int MODE>
__global__ __launch_bounds__(256) void gemm_k256(
    const uchar* __restrict__ A, const uchar* __restrict__ Bt,
    const float* __restrict__ bias,
    uchar* __restrict__ out8, bf16* __restrict__ xres,
    int N, int nTiles,
    const float* __restrict__ bq, const float* __restrict__ bk)
{
  __shared__ __align__(16) char smem[65536];   // As 32K | Bs 32K ; staging aliases
  uchar* As = (uchar*)smem;
  uchar* Bs = (uchar*)(smem + 32768);
  uchar* S8 = (uchar*)smem;                    // fp8 staging, stride 136, 128 rows
  bf16 (*Cs)[136] = (bf16 (*)[136])smem;       // bf16 staging (MODE3 halves)
  int chunk = gridDim.x >> 3;
  int bi = (blockIdx.x & 7) * chunk + (blockIdx.x >> 3);
  int m0 = (bi / nTiles) * 128, n0 = (bi % nTiles) * 128;
  int tid = threadIdx.x;
  int wave = tid >> 6, lane = tid & 63;
  int wm = (wave >> 1) * 64, wn = (wave & 1) * 64;
  int r32 = lane & 31, half = lane >> 5;

  // stage full K: coalesced (c = row*16 + p), XOR within the row.
  #pragma unroll
  for (int j = 0; j < 8; j++){
    int c = j * 256 + tid;
    int row = c >> 4, p = c & 15;
    int sl = (p & 8) | ((p & 7) ^ (row & 7));
    gl_lds16(A  + (size_t)(m0 + row) * 256 + sl * 16, As + (size_t)c * 16);
    gl_lds16(Bt + (size_t)(n0 + row) * 256 + sl * 16, Bs + (size_t)c * 16);
  }

  f32x16 acc[2][2];
  #pragma unroll
  for (int mb = 0; mb < 2; mb++)
    #pragma unroll
    for (int nb = 0; nb < 2; nb++)
      #pragma unroll
      for (int e = 0; e < 16; e++) acc[mb][nb][e] = 0.f;

  __syncthreads();   // single barrier: all 64KB staged

  #pragma unroll
  for (int c = 0; c < 8; c++){
    int l0 = 2 * c + half;                       // logical 16B chunk
    i64 alo[2], ahi[2], blo[2], bhi[2];
    #pragma unroll
    for (int mb = 0; mb < 2; mb++){
      int row = wm + mb * 32 + r32;
      int st = (l0 & 8) | ((l0 & 7) ^ (row & 7));
      uint4 v = *(const uint4*)(As + row * 256 + st * 16);
      alo[mb] = *(const i64*)&v.x;  ahi[mb] = *(const i64*)&v.z;
    }
    #pragma unroll
    for (int nb = 0; nb < 2; nb++){
      int row = wn + nb * 32 + r32;
      int st = (l0 & 8) | ((l0 & 7) ^ (row & 7));
      uint4 v = *(const uint4*)(Bs + row * 256 + st * 16);
      blo[nb] = *(const i64*)&v.x;  bhi[nb] = *(const i64*)&v.z;
    }
    #pragma unroll
    for (int mb = 0; mb < 2; mb++)
      #pragma unroll
      for (int nb = 0; nb < 2; nb++){
        if (MODE == 5){
          acc[mb][nb] = __builtin_amdgcn_mfma_f32_32x32x16_fp8_fp8(alo[mb], blo[nb], acc[mb][nb], 0, 0, 0);
          acc[mb][nb] = __builtin_amdgcn_mfma_f32_32x32x16_fp8_fp8(ahi[mb], bhi[nb], acc[mb][nb], 0, 0, 0);
        } else {   // swapped: D rows = n, cols = m
          acc[mb][nb] = __builtin_amdgcn_mfma_f32_32x32x16_fp8_fp8(blo[nb], alo[mb], acc[mb][nb], 0, 0, 0);
          acc[mb][nb] = __builtin_amdgcn_mfma_f32_32x32x16_fp8_fp8(bhi[nb], ahi[mb], acc[mb][nb], 0, 0, 0);
        }
      }
  }

  __syncthreads();   // As/Bs dead; staging aliases

  // 32x32 D layout: "col" = lane&31, "row" = (reg&3) + 8*(reg>>2) + 4*half.
  if (MODE == 4){
    const int region = n0 >> 8;
    const float* bb = (region == 0 ? bq : bk);
    // swapped: m = lane&31 (fixed), reg-quad g = 4 consecutive n. Staging [m][n].
    #pragma unroll
    for (int mb = 0; mb < 2; mb++){
      int m_l = wm + mb * 32 + r32;
      #pragma unroll
      for (int nb = 0; nb < 2; nb++)
        #pragma unroll
        for (int g = 0; g < 4; g++){
          int n_l = wn + nb * 32 + g * 8 + half * 4;
          int bidx = (n0 & 255) + n_l;
          float v0 = acc[mb][nb][g * 4 + 0] + bb[bidx + 0];
          float v1 = acc[mb][nb][g * 4 + 1] + bb[bidx + 1];
          float v2 = acc[mb][nb][g * 4 + 2] + bb[bidx + 2];
          float v3 = acc[mb][nb][g * 4 + 3] + bb[bidx + 3];
          *(unsigned*)(S8 + m_l * 136 + n_l) = pack4_fp8(v0, v1, v2, v3);
        }
    }
    __syncthreads();
    int lr = tid >> 1, seg = tid & 1;
    #pragma unroll
    for (int j = 0; j < 4; j++){
      int nl = seg * 64 + j * 16;
      uint2 a = *(uint2*)(S8 + lr * 136 + nl);
      uint2 b = *(uint2*)(S8 + lr * 136 + nl + 8);
      uint4 st = make_uint4(a.x, a.y, b.x, b.y);
      int m = m0 + lr;
      int b_ = m / 360, s = m - b_ * 360;
      int nnl = (n0 & 255) + nl;
      int h = nnl >> 6, dk = nnl & 63;
      size_t roff = (region == 1) ? 23592960ull : 0ull;
      *(uint4*)(out8 + roff + ((size_t)(b_ * 4 + h) * 360 + s) * 64 + dk) = st;
    }
  } else if (MODE == 5){
    // unswapped: n = lane&31 (fixed), reg-quad g = 4 consecutive m. Staging [n][m].
    #pragma unroll
    for (int nb = 0; nb < 2; nb++){
      int n_l = wn + nb * 32 + r32;
      float bv_ = bias[n0 + n_l];
      #pragma unroll
      for (int mb = 0; mb < 2; mb++)
        #pragma unroll
        for (int g = 0; g < 4; g++){
          int m_l = wm + mb * 32 + g * 8 + half * 4;
          *(unsigned*)(S8 + n_l * 136 + m_l) =
              pack4_fp8(acc[mb][nb][g * 4 + 0] + bv_, acc[mb][nb][g * 4 + 1] + bv_,
                        acc[mb][nb][g * 4 + 2] + bv_, acc[mb][nb][g * 4 + 3] + bv_);
        }
    }
    __syncthreads();
    int nn = tid >> 1, part = tid & 1;
    int nnl = n0 + nn;                    // N=256
    int h = nnl >> 6, dk = nnl & 63;
    #pragma unroll
    for (int j0 = 0; j0 < 64; j0 += 8){
      int mm = m0 + part * 64 + j0;       // 8-aligned; 360%8==0 -> no batch cross
      int b_ = mm / 360, s = mm - b_ * 360;
      uint2 val = *(uint2*)(S8 + nn * 136 + part * 64 + j0);
      *(uint2*)(out8 + ((size_t)((b_ * 4 + h) * 64 + dk)) * 360 + s) = val;
    }
  } else {  // MODE 3: bf16 residual, halves, swapped orientation
    #pragma unroll
    for (int hb = 0; hb < 2; hb++){
      if ((wave >> 1) == hb){
        #pragma unroll
        for (int mb = 0; mb < 2; mb++){
          int ml = mb * 32 + r32;               // local to half
          #pragma unroll
          for (int nb = 0; nb < 2; nb++)
            #pragma unroll
            for (int g = 0; g < 4; g++){
              int nl0 = wn + nb * 32 + g * 8 + half * 4;
              float v0 = acc[mb][nb][g * 4 + 0] + bias[n0 + nl0 + 0];
              float v1 = acc[mb][nb][g * 4 + 1] + bias[n0 + nl0 + 1];
              float v2 = acc[mb][nb][g * 4 + 2] + bias[n0 + nl0 + 2];
              float v3 = acc[mb][nb][g * 4 + 3] + bias[n0 + nl0 + 3];
              *(unsigned*)(&Cs[ml][nl0])     = pack2(v0, v1);
              *(unsigned*)(&Cs[ml][nl0 + 2]) = pack2(v2, v3);
            }
        }
      }
      __syncthreads();
      int mbase = m0 + hb * 64;
      int lr = tid >> 2, seg = tid & 3;
      bf16* op = xres + (size_t)(mbase + lr) * 256 + n0 + seg * 32;
      #pragma unroll
      for (int j = 0; j < 4; j++){
        uint4 cv = *(uint4*)(&Cs[lr][seg * 32 + j * 8]);
        uint4 xv = *(uint4*)(op + j * 8);
        bf16* ca = (bf16*)&cv; bf16* xa = (bf16*)&xv;
        bf16 o8[8];
        #pragma unroll
        for (int t = 0; t < 8; t++)
          o8[t] = __float2bfloat16(__bfloat162float(ca[t]) + __bfloat162float(xa[t]));
        *(uint4*)(op + j * 8) = *(uint4*)o8;
      }
      __syncthreads();
    }
  }
}

// ---------------------------------------------------------------------------
// Fused FFN v2: 64-row M-tile, 256 thr (4 waves), single-buffered slab,
// 80KB LDS -> TWO independent blocks/CU (cross-block TLP covers the serial
// slab chain). x += (relu(xn8 @ W1 + b1) @ W2 + b2).
// LDS: A 16K @0 | W1/h 32K @16384 | W2 32K @49152.  R21 3-bit XOR swizzles.
// Per slab: FFN1 -> lgkm bar -> h -> lgkm bar -> FFN2 -> lgkm bar ->
// stage s+1 -> __syncthreads (vmcnt drain).
// Epilogue: collision-free Cs stride 264 (fixes R18 aliasing, absmax 0.64).
// ---------------------------------------------------------------------------
__global__ __launch_bounds__(256) void gemm_ffn(
    const uchar* __restrict__ A, const uchar* __restrict__ W1t,
    const uchar* __restrict__ W2t, const float* __restrict__ b1,
    const float* __restrict__ b2, bf16* __restrict__ xres)
{
  extern __shared__ __align__(16) char sm[];
  const int W1OFF = 16384, W2OFF = 49152;
  int bi = (blockIdx.x & 7) * 180 + (blockIdx.x >> 3);   // 1440 = 8*180
  int m0 = bi * 64;
  int tid = threadIdx.x;
  int wave = tid >> 6, lane = tid & 63;
  int wn  = wave * 64;                   // FFN2: n-offset (4 waves x 64n)
  int wnh = wave * 32;                   // FFN1: h-offset (4 waves x 32h)
  int r32 = lane & 31, half = lane >> 5;

  // stage A tile (64 rows x 256B), coalesced, XOR within row.
  #pragma unroll
  for (int j = 0; j < 4; j++){
    int c = j * 256 + tid;
    int row = c >> 4, p = c & 15;
    int sl = (p & 8) | ((p & 7) ^ (row & 7));
    gl_lds16(A + (size_t)(m0 + row) * 256 + sl * 16, sm + c * 16);
  }
  // stage W slab 0.
  #pragma unroll
  for (int j = 0; j < 8; j++){
    int c = j * 256 + tid;
    int row1 = c >> 4, p1 = c & 15;
    int sl1 = (p1 & 8) | ((p1 & 7) ^ (row1 & 7));
    gl_lds16(W1t + (size_t)row1 * 256 + sl1 * 16, sm + W1OFF + c * 16);
    int row2 = c >> 3, p2 = c & 7;
    int sl2 = p2 ^ (row2 & 7);
    gl_lds16(W2t + (size_t)row2 * 2048 + sl2 * 16, sm + W2OFF + c * 16);
  }

  f32x16 acc2[2][2];
  #pragma unroll
  for (int mb = 0; mb < 2; mb++)
    #pragma unroll
    for (int nb = 0; nb < 2; nb++)
      #pragma unroll
      for (int e = 0; e < 16; e++) acc2[mb][nb][e] = 0.f;

  __syncthreads();    // drains all staging

  // hoist A fragments (whole 64-row tile per wave) to registers.
  i64 Alo[2][8], Ahi[2][8];
  #pragma unroll
  for (int c = 0; c < 8; c++){
    int l0 = 2 * c + half;
    #pragma unroll
    for (int mb = 0; mb < 2; mb++){
      int row = mb * 32 + r32;
      int st = (l0 & 8) | ((l0 & 7) ^ (row & 7));
      uint4 v = *(const uint4*)(sm + row * 256 + st * 16);
      Alo[mb][c] = *(const i64*)&v.x;  Ahi[mb][c] = *(const i64*)&v.z;
    }
  }

  for (int s = 0; s < 16; s++){
    // FFN1: acc1 = A(regs) @ W1_slab^T (swapped: D rows = hidden, cols = m)
    f32x16 acc1[2];
    #pragma unroll
    for (int mb = 0; mb < 2; mb++)
      #pragma unroll
      for (int e = 0; e < 16; e++) acc1[mb][e] = 0.f;
    #pragma unroll
    for (int c = 0; c < 8; c++){
      int l0 = 2 * c + half;
      int roww = wnh + r32;
      int stw = (l0 & 8) | ((l0 & 7) ^ (roww & 7));
      uint4 w = *(const uint4*)(sm + W1OFF + roww * 256 + stw * 16);
      i64 wlo = *(const i64*)&w.x, whi = *(const i64*)&w.z;
      #pragma unroll
      for (int mb = 0; mb < 2; mb++){
        acc1[mb] = __builtin_amdgcn_mfma_f32_32x32x16_fp8_fp8(wlo, Alo[mb][c], acc1[mb], 0, 0, 0);
        acc1[mb] = __builtin_amdgcn_mfma_f32_32x32x16_fp8_fp8(whi, Ahi[mb][c], acc1[mb], 0, 0, 0);
      }
    }
    barrier_lgkm();     // all waves done reading W1[s]

    // h = relu(acc1 + b1) -> fp8 over W1 region: [64 m][128 hid], 3-bit XOR
    #pragma unroll
    for (int mb = 0; mb < 2; mb++){
      int m = mb * 32 + r32;
      #pragma unroll
      for (int g = 0; g < 4; g++){
        int n_l = wnh + g * 8 + half * 4;
        float4 bv = *(const float4*)(b1 + s * 128 + n_l);
        float v0 = fmaxf(acc1[mb][g * 4 + 0] + bv.x, 0.f);
        float v1 = fmaxf(acc1[mb][g * 4 + 1] + bv.y, 0.f);
        float v2 = fmaxf(acc1[mb][g * 4 + 2] + bv.z, 0.f);
        float v3 = fmaxf(acc1[mb][g * 4 + 3] + bv.w, 0.f);
        int sl = (n_l >> 4) ^ (m & 7);
        *(unsigned*)(sm + W1OFF + m * 128 + sl * 16 + (n_l & 15)) =
            pack4_fp8(v0, v1, v2, v3);
      }
    }
    barrier_lgkm();     // h visible

    // FFN2: acc2 += h @ W2_slab (swapped: D rows = out-col, cols = m)
    #pragma unroll
    for (int c = 0; c < 4; c++){
      int l0 = 2 * c + half;
      i64 hlo[2], hhi[2], wlo[2], whi[2];
      #pragma unroll
      for (int mb = 0; mb < 2; mb++){
        int row = mb * 32 + r32;
        int st = l0 ^ (row & 7);
        uint4 v = *(const uint4*)(sm + W1OFF + row * 128 + st * 16);
        hlo[mb] = *(const i64*)&v.x;  hhi[mb] = *(const i64*)&v.z;
      }
      #pragma unroll
      for (int nb = 0; nb < 2; nb++){
        int row = wn + nb * 32 + r32;
        int st = l0 ^ (row & 7);
        uint4 v = *(const uint4*)(sm + W2OFF + row * 128 + st * 16);
        wlo[nb] = *(const i64*)&v.x;  whi[nb] = *(const i64*)&v.z;
      }
      #pragma unroll
      for (int mb = 0; mb < 2; mb++)
        #pragma unroll
        for (int nb = 0; nb < 2; nb++){
          acc2[mb][nb] = __builtin_amdgcn_mfma_f32_32x32x16_fp8_fp8(wlo[nb], hlo[mb], acc2[mb][nb], 0, 0, 0);
          acc2[mb][nb] = __builtin_amdgcn_mfma_f32_32x32x16_fp8_fp8(whi[nb], hhi[mb], acc2[mb][nb], 0, 0, 0);
        }
    }
    barrier_lgkm();     // all waves done reading W1(h)/W2 -> safe to overwrite

    // stage slab s+1 (single buffer; the co-resident block hides this)
    if (s < 15){
      #pragma unroll
      for (int j = 0; j < 8; j++){
        int c = j * 256 + tid;
        int row1 = c >> 4, p1 = c & 15;
        int sl1 = (p1 & 8) | ((p1 & 7) ^ (row1 & 7));
        gl_lds16(W1t + (size_t)((s + 1) * 128 + row1) * 256 + sl1 * 16,
                 sm + W1OFF + c * 16);
        int row2 = c >> 3, p2 = c & 7;
        int sl2 = p2 ^ (row2 & 7);
        gl_lds16(W2t + (size_t)row2 * 2048 + (s + 1) * 128 + sl2 * 16,
                 sm + W2OFF + c * 16);
      }
      __syncthreads();  // drain vmcnt: slab s+1 ready
    }
  }

  // epilogue: acc2 + b2 -> bf16 Cs [64][264] (collision-free), RMW x.
  bf16 (*Cs)[264] = (bf16 (*)[264])(sm + W1OFF);
  #pragma unroll
  for (int mb = 0; mb < 2; mb++){
    int ml = mb * 32 + r32;
    #pragma unroll
    for (int nb = 0; nb < 2; nb++)
      #pragma unroll
      for (int g = 0; g < 4; g++){
        int nl0 = wn + nb * 32 + g * 8 + half * 4;
        float4 bv = *(const float4*)(b2 + nl0);
        float v0 = acc2[mb][nb][g * 4 + 0] + bv.x;
        float v1 = acc2[mb][nb][g * 4 + 1] + bv.y;
        float v2 = acc2[mb][nb][g * 4 + 2] + bv.z;
        float v3 = acc2[mb][nb][g * 4 + 3] + bv.w;
        *(unsigned*)(&Cs[ml][nl0])     = pack2(v0, v1);
        *(unsigned*)(&Cs[ml][nl0 + 2]) = pack2(v2, v3);
      }
  }
  barrier_lgkm();
  int lr = tid >> 2, seg = tid & 3;
  bf16* op = xres + (size_t)(m0 + lr) * 256 + seg * 64;
  #pragma unroll
  for (int j = 0; j < 8; j++){
    uint4 cv = *(uint4*)(&Cs[lr][seg * 64 + j * 8]);
    uint4 xv = *(uint4*)(op + j * 8);
    bf16* ca = (bf16*)&cv; bf16* xa = (bf16*)&xv;
    bf16 o8[8];
    #pragma unroll
    for (int t = 0; t < 8; t++)
      o8[t] = __float2bfloat16(__bfloat162float(ca[t]) + __bfloat162float(xa[t]));
    *(uint4*)(op + j * 8) = *(uint4*)o8;
  }
}

// attn5 kc-step. TAIL=true only for kc=11 (keys 352..383): row clamps +
// key<360 zeroing live only there (p1 is compile-time dead in tail).
template<bool TAIL>
static __device__ __forceinline__ void attn_step(
    int kc, const uchar (*Ks)[80], uchar (*Pb)[16][48],
    const uchar* __restrict__ vb, int wave, int r, int qd,
    const i64* qa0, const i64* qa1, float* lsum, f32x4 (*accO)[4])
{
  int krow0 = kc * 32 + r;
  int krow1 = krow0 + 16;
  if (TAIL){ if (krow0 > 359) krow0 = 359; if (krow1 > 359) krow1 = 359; }
  i64 kf00 = *(const i64*)(&Ks[krow0][qd * 8]);
  i64 kf01 = *(const i64*)(&Ks[krow0][32 + qd * 8]);
  i64 kf10 = *(const i64*)(&Ks[krow1][qd * 8]);
  i64 kf11 = *(const i64*)(&Ks[krow1][32 + qd * 8]);
  i64 vf[4];
  #pragma unroll
  for (int dt = 0; dt < 4; dt++)
    vf[dt] = *(const i64*)(vb + (size_t)(dt * 16 + r) * 360 + kc * 32 + qd * 8);

  const float CEXP = 0.18033688011112042f;   // 0.125 * log2(e)

  #pragma unroll
  for (int tl = 0; tl < 3; tl++){
    f32x4 z0 = {0.f, 0.f, 0.f, 0.f}, z1 = {0.f, 0.f, 0.f, 0.f};
    z0 = __builtin_amdgcn_mfma_f32_16x16x32_fp8_fp8(kf00, qa0[tl], z0, 0, 0, 0);
    z0 = __builtin_amdgcn_mfma_f32_16x16x32_fp8_fp8(kf01, qa1[tl], z0, 0, 0, 0);
    z1 = __builtin_amdgcn_mfma_f32_16x16x32_fp8_fp8(kf10, qa0[tl], z1, 0, 0, 0);
    z1 = __builtin_amdgcn_mfma_f32_16x16x32_fp8_fp8(kf11, qa1[tl], z1, 0, 0, 0);
    float p0[4], p1[4];
    #pragma unroll
    for (int i = 0; i < 4; i++){
      p0[i] = fexp2(z0[i] * CEXP);
      p1[i] = fexp2(z1[i] * CEXP);
      if (TAIL){
        if (kc * 32 + qd * 4 + i >= 360) p0[i] = 0.f;
        if (kc * 32 + 16 + qd * 4 + i >= 360) p1[i] = 0.f;
      }
      lsum[tl] += p0[i] + p1[i];
    }
    *(unsigned*)(&Pb[wave][r][qd * 4])      = pack4_fp8(p0[0], p0[1], p0[2], p0[3]);
    *(unsigned*)(&Pb[wave][r][16 + qd * 4]) = pack4_fp8(p1[0], p1[1], p1[2], p1[3]);
    asm volatile("s_waitcnt lgkmcnt(0)" ::: "memory");
    i64 pa = *(const i64*)(&Pb[wave][r][qd * 8]);
    // swapped PV: D[d_local=qd*4+i][q=r] -> lane holds 4 consecutive d at q=r
    #pragma unroll
    for (int dt = 0; dt < 4; dt++)
      accO[tl][dt] = __builtin_amdgcn_mfma_f32_16x16x32_fp8_fp8(pa, vf[dt], accO[tl][dt], 0, 0, 0);
    asm volatile("s_waitcnt lgkmcnt(0)" ::: "memory");
  }
}

// attn5: fp8 flash attention. one block per (b,h) [1024], 512 thr / 8 waves,
// 3 q-tiles/wave, single-pass softmax (pad queries: Q zeroed -> uniform).
__global__ __launch_bounds__(512) void attn5(
    const uchar* __restrict__ q, const uchar* __restrict__ kk, const uchar* __restrict__ vt,
    const int* __restrict__ src, uchar* __restrict__ ctx8)
{
  __shared__ __align__(16) uchar smem[34944];            // Ks 28800 | Pb 6144
  uchar (*Ks)[80]     = (uchar (*)[80])smem;             // [360][80]
  uchar (*Pb)[16][48] = (uchar (*)[16][48])(smem + 28800); // [8][16][48]
  int bh = blockIdx.x;
  int b = bh >> 2, h = bh & 3;
  int wave = threadIdx.x >> 6, lane = threadIdx.x & 63;
  int r = lane & 15, qd = lane >> 4;
  const uchar* qb = q  + (size_t)bh * 360 * 64;
  const uchar* kb = kk + (size_t)bh * 360 * 64;
  const uchar* vb = vt + (size_t)bh * 64 * 360;
  const int* srow = src + b * 360;

  for (int c = threadIdx.x; c < 1440; c += 512){
    int row = c >> 2, g = c & 3;
    *(uint4*)(&Ks[row][g * 16]) = *(const uint4*)(kb + row * 64 + g * 16);
  }
  __syncthreads();

  i64 qa0[3], qa1[3];
  float lsum[3];
  f32x4 accO[3][4];
  #pragma unroll
  for (int tl = 0; tl < 3; tl++){
    int qt = wave * 3 + tl;
    int qg = qt * 16 + r;
    int qrow = qg > 359 ? 359 : qg;
    bool qp = (qg < 360) && (srow[qg] == 799);
    i64 a0 = *(const i64*)(qb + qrow * 64 + qd * 8);
    i64 a1 = *(const i64*)(qb + qrow * 64 + 32 + qd * 8);
    qa0[tl] = qp ? 0 : a0;          // pad query: Q=0 -> z=0 -> p=1 (uniform)
    qa1[tl] = qp ? 0 : a1;
    lsum[tl] = 0.f;
    #pragma unroll
    for (int dt = 0; dt < 4; dt++) accO[tl][dt] = (f32x4){0.f, 0.f, 0.f, 0.f};
  }

  for (int kc = 0; kc < 11; kc++)
    attn_step<false>(kc, Ks, Pb, vb, wave, r, qd, qa0, qa1, lsum, accO);
  attn_step<true>(11, Ks, Pb, vb, wave, r, qd, qa0, qa1, lsum, accO);

  __syncthreads();                  // all waves past Ks reads; Cb aliases Ks
  uchar* Cw = smem + wave * 1280;   // per-wave [16][80] staging over dead Ks

  #pragma unroll
  for (int tl = 0; tl < 3; tl++){
    float ls = lsum[tl];
    ls += __shfl_xor(ls, 16, 64);
    ls += __shfl_xor(ls, 32, 64);
    float invl = 1.0f / ls;         // lane-local: accO cols are own q=r
    #pragma unroll
    for (int dt = 0; dt < 4; dt++)
      *(unsigned*)(Cw + r * 80 + dt * 16 + qd * 4) =
          pack4_fp8(accO[tl][dt][0] * invl, accO[tl][dt][1] * invl,
                    accO[tl][dt][2] * invl, accO[tl][dt][3] * invl);
    asm volatile("s_waitcnt lgkmcnt(0)" ::: "memory");
    int qt = wave * 3 + tl;
    int qglob = qt * 16 + r;
    if (qglob < 360)
      *(uint4*)(ctx8 + ((size_t)(b * 360 + qglob)) * 256 + h * 64 + qd * 16) =
          *(uint4*)(Cw + r * 80 + qd * 16);
    asm volatile("s_waitcnt lgkmcnt(0)" ::: "memory");
  }
}

// head: one block per batch (grid 256, 4 waves).
__global__ __launch_bounds__(256) void head_k(
    const bf16* __restrict__ x, const int* __restrict__ src,
    const float* __restrict__ wl, const float* __restrict__ bl,
    float* __restrict__ out)
{
  __shared__ bf16 Xs[192][264];
  int b = blockIdx.x;
  int tid = threadIdx.x;
  int wave = tid >> 6, lane = tid & 63;
  int g = lane >> 3, sub = lane & 7;

  const bf16* xb = x + (size_t)b * 360 * 256;
  for (int it = 0; it < 24; it++){
    int idx = tid + it * 256;
    int row = idx >> 5, col = idx & 31;
    *(uint4*)(&Xs[row][col * 8]) = *(const uint4*)(xb + row * 256 + col * 8);
  }

  float wv[96];
  {
    const float4* wr4 = (const float4*)(wl + (size_t)(g * 256 + sub * 32) * 3);
    #pragma unroll
    for (int c = 0; c < 24; c++) *(float4*)(&wv[c * 4]) = wr4[c];
  }
  float bl0 = bl[0], bl1 = bl[1], bl2 = bl[2];
  const int* sr = src + b * 360;
  __syncthreads();

  for (int p = wave; p < 91; p += 4){
    int i = 0, rem = p;
    while (rem >= 13 - i){ rem -= 13 - i; i++; }
    int j = i + 1 + rem;
    int base = 12 * i - (i * (i - 1)) / 2;
    int pe = base + (j - i) - 1;
    int eb = 28 + 2 * pe;

    int idxg;
    if (g == 0) idxg = 2 * i;
    else if (g == 1) idxg = 2 * i + 1;
    else if (g == 2) idxg = 2 * j;
    else if (g == 3) idxg = 2 * j + 1;
    else idxg = eb + (g - 4);
    bool zm = !(g >= 4 && j == 13);

    uint4 xv[4];
    #pragma unroll
    for (int c = 0; c < 4; c++) xv[c] = *(uint4*)(&Xs[idxg][sub * 32 + c * 8]);
    const bf16* xa = (const bf16*)xv;
    float a0 = 0.f, a1 = 0.f, a2 = 0.f;
    #pragma unroll
    for (int t = 0; t < 32; t++){
      float f = zm ? __bfloat162float(xa[t]) : 0.0f;
      a0 += f * wv[t * 3 + 0];
      a1 += f * wv[t * 3 + 1];
      a2 += f * wv[t * 3 + 2];
    }
    #pragma unroll
    for (int o = 1; o < 64; o <<= 1){
      a0 += __shfl_xor(a0, o, 64);
      a1 += __shfl_xor(a1, o, 64);
      a2 += __shfl_xor(a2, o, 64);
    }
    if (lane == 0){
      int ti = sr[2 * i], ai = sr[2 * i + 1], tj = sr[2 * j], aj = sr[2 * j + 1];
      bool c1 = (ai == 2) || (aj == 2);
      bool c2 = (tj == 1) || (ai == 1) || (aj == 1);
      bool c3 = (ti == 799) || (tj == 799) || (ai == 0) || (aj == 0);
      bool c4 = false;
      if (j < 13){
        int es = 28 + 4 * pe;
        c4 = (sr[es] == 1) || (sr[es + 1] == 1) || (sr[es + 2] == 1) || (sr[es + 3] == 1);
      }
      bool m1 = c3 || c4, m2 = m1 || c2, m3 = m2 || c1;
      float* op = out + ((size_t)b * 91 + p) * 3;
      op[0] = m1 ? -1.0e9f : (a0 + bl0);
      op[1] = m2 ? -1.0e9f : (a1 + bl1);
      op[2] = m3 ? -1.0e9f : (a2 + bl2);
    }
  }
}

extern "C" void kernel_launch(void* const* d_in, const int* in_sizes, int n_in,
                              void* d_out, int out_size, void* d_ws, size_t ws_size,
                              hipStream_t stream)
{
  const int*   src = (const int*)  d_in[0];
  const float* emb = (const float*)d_in[1];
  const float* wq  = (const float*)d_in[2];  const float* bq = (const float*)d_in[3];
  const float* wk  = (const float*)d_in[4];  const float* bk = (const float*)d_in[5];
  const float* wv  = (const float*)d_in[6];  const float* bv = (const float*)d_in[7];
  const float* wo  = (const float*)d_in[8];  const float* bo = (const float*)d_in[9];
  const float* n1a = (const float*)d_in[10]; const float* n1b = (const float*)d_in[11];
  const float* n2a = (const float*)d_in[12]; const float* n2b = (const float*)d_in[13];
  const float* w1  = (const float*)d_in[14]; const float* b1 = (const float*)d_in[15];
  const float* w2  = (const float*)d_in[16]; const float* b2 = (const float*)d_in[17];
  const float* wl  = (const float*)d_in[18]; const float* bl = (const float*)d_in[19];
  float* out = (float*)d_out;

  if (ws_size < 191365120ull) return;

  char* ws = (char*)d_ws;
  bf16*  x    = (bf16*)(ws);                   // [92160][256] bf16
  uchar* xn8  = (uchar*)(ws + 47185920ull);    // [92160][256] fp8: LN1 / ctx8 / LN2
  char*  R    = ws + 70778880ull;
  uchar* q8   = (uchar*)(R);                   // [1024][360][64]; k8 +23592960
  uchar* vt8  = (uchar*)(R + 47185920ull);     // [1024][64][360]
  char*  wC   = ws + 165150720ull;             // weights at workspace tail
  uchar* wqkv8 = (uchar*)(wC);                 // [768][256] fp8
  uchar* wo8   = (uchar*)(wC + 196608);        // [256][256] fp8
  uchar* w1f8T = (uchar*)(wC + 262144);        // [2048][256] fp8
  uchar* w2f8T = (uchar*)(wC + 786432);        // [256][2048] fp8  (end 166461440)

  cvt_all<<<1280, 256, 0, stream>>>(wq, wk, wv, wo, w1, w2,
                                    wqkv8, wqkv8 + 65536, wqkv8 + 131072,
                                    wo8, w1f8T, w2f8T);

  embed_ln1<<<23040, 256, 0, stream>>>(src, emb, n1a, n1b, x, xn8);

  // QK: N=512 (rows 0..511 of wqkv8), 720x4 = 2880 blocks.
  gemm_k256<4><<<2880, 256, 0, stream>>>(xn8, wqkv8, nullptr, q8, nullptr,
                                         512, 4, bq, bk);
  // V: N=256 (rows 512..767), MODE5 -> vt8. 720x2 = 1440 blocks.
  gemm_k256<5><<<1440, 256, 0, stream>>>(xn8, wqkv8 + 131072, bv, vt8, nullptr,
                                         256, 2, nullptr, nullptr);

  attn5<<<1024, 512, 0, stream>>>(q8, q8 + 23592960ull, vt8, src, xn8 /* ctx8 */);

  gemm_k256<3><<<1440, 256, 0, stream>>>(xn8, wo8, bo, nullptr, x,
                                         256, 2, nullptr, nullptr);

  ln_k8<<<23040, 256, 0, stream>>>(x, n2a, n2b, xn8);

  // fused FFN v2: 1440 blocks x 256 thr, 80KB LDS -> 2 blocks/CU.
  gemm_ffn<<<1440, 256, 81920, stream>>>(xn8, w1f8T, w2f8T, b1, b2, x);

  head_k<<<256, 256, 0, stream>>>(x, src, wl, bl, out);
}

// Round 12
// 494.841 us; speedup vs baseline: 1.1129x; 1.1129x over previous
//
#include <hip/hip_runtime.h>
#include <hip/hip_bf16.h>
#include <math.h>

// ---------------------------------------------------------------------------
// Round 25: bank R21 (best: 498us) + collision-free epilogue only.
// R24 post-mortem: 2-blocks/CU failed (occ 10.7% = 1 block; 2x81920 = exact
// 160KiB, no slack) and single-buffer serialization made it worse (253us).
// But absmax 0.64->0.25 validated the epilogue aliasing fix (Cs[136] with
// nl0<256 collided across rows). This round = R21 structure exactly
// (128-row tile, 512thr, dbuf slabs, A-in-regs, 3-bit XOR) with Cs stride
// 264 (67.6KB in the dead W region). All other knobs proven local-optimal:
// setprio(-), prefetch-at-top(-), 4-bit XOR(-), k-plane(-), 2-block(-).
// ---------------------------------------------------------------------------

using bf16 = __hip_bfloat16;
typedef __attribute__((ext_vector_type(4))) float f32x4;
typedef __attribute__((ext_vector_type(16))) float f32x16;
typedef long long i64;
typedef unsigned char uchar;

static __device__ __forceinline__ float wave_sum64(float v){
  #pragma unroll
  for (int o = 32; o >= 1; o >>= 1) v += __shfl_xor(v, o, 64);
  return v;
}

static __device__ __forceinline__ void gl_lds16(const void* g, void* l){
  __builtin_amdgcn_global_load_lds((const __attribute__((address_space(1))) void*)g,
                                   (__attribute__((address_space(3))) void*)l, 16, 0, 0);
}

// barrier that orders LDS ops only -- leaves vmcnt (prefetch) in flight.
static __device__ __forceinline__ void barrier_lgkm(){
  asm volatile("s_waitcnt lgkmcnt(0)" ::: "memory");
  __builtin_amdgcn_s_barrier();
}

static __device__ __forceinline__ unsigned pack2(float a, float b){
  union { bf16 h[2]; unsigned u; } u;
  u.h[0] = __float2bfloat16(a); u.h[1] = __float2bfloat16(b);
  return u.u;
}

static __device__ __forceinline__ uchar f2f8(float v){
  return (uchar)(__builtin_amdgcn_cvt_pk_fp8_f32(v, 0.f, 0, false) & 0xff);
}
static __device__ __forceinline__ unsigned pack4_fp8(float a, float b, float c, float d){
  int v = __builtin_amdgcn_cvt_pk_fp8_f32(a, b, 0, false);
  v = __builtin_amdgcn_cvt_pk_fp8_f32(c, d, v, true);
  return (unsigned)v;
}

// 2^x in one instruction (non-volatile: dead results get DCE'd).
static __device__ __forceinline__ float fexp2(float x){
  float r;
  asm("v_exp_f32 %0, %1" : "=v"(r) : "v"(x));
  return r;
}

// merged weight prep: all 6 jobs fp8 transposed. 1280 blocks.
__global__ __launch_bounds__(256) void cvt_all(
    const float* s0, const float* s1, const float* s2, const float* s3,
    const float* s4, const float* s5,
    uchar* d0, uchar* d1, uchar* d2, uchar* d3, uchar* d4, uchar* d5)
{
  __shared__ float t[32][33];
  const float* srcs[6] = {s0, s1, s2, s3, s4, s5};
  uchar* dsts[6] = {d0, d1, d2, d3, d4, d5};
  const int Ks[6] = {256, 256, 256, 256, 256, 2048};
  const int Ns[6] = {256, 256, 256, 256, 2048, 256};
  const int offs[7] = {0, 64, 128, 192, 256, 768, 1280};
  int bid = blockIdx.x, j = 5;
  #pragma unroll
  for (int q = 4; q >= 0; q--) if (bid < offs[q + 1]) j = q;
  int local = bid - offs[j];
  int K = Ks[j], N = Ns[j];
  const float* src = srcs[j];
  uchar* dst = dsts[j];
  int kt = K >> 5;
  int kb = (local % kt) * 32, nb = (local / kt) * 32;
  int tx = threadIdx.x & 31, ty = threadIdx.x >> 5;
  #pragma unroll
  for (int dy = 0; dy < 32; dy += 8)
    t[ty + dy][tx] = src[(size_t)(kb + ty + dy) * N + nb + tx];
  __syncthreads();
  #pragma unroll
  for (int dy = 0; dy < 32; dy += 8)
    dst[(size_t)(nb + ty + dy) * K + kb + tx] = f2f8(t[tx][ty + dy]);
}

// embed + PE + scale -> x (bf16), LN1 -> fp8 xn8. one wave/row, grid 23040.
__global__ __launch_bounds__(256) void embed_ln1(
    const int* __restrict__ src, const float* __restrict__ emb,
    const float* __restrict__ na, const float* __restrict__ nb,
    bf16* __restrict__ x, uchar* __restrict__ xn8)
{
  int row  = blockIdx.x * 4 + (threadIdx.x >> 6);
  int lane = threadIdx.x & 63;
  int s = row % 360;
  int tok = src[row];
  float4 v = *(const float4*)(emb + (size_t)tok * 256 + lane * 4);
  float vv[4] = {v.x, v.y, v.z, v.w};
  if (s < 340){
    const float C = (-2.0f / 256.0f) * 13.287712379549449f;
    #pragma unroll
    for (int t = 0; t < 4; t++){
      int c = lane * 4 + t;
      float ang = (float)s * exp2f(C * (float)c);
      float pe = (c & 1) ? cosf(ang) : sinf(ang);
      vv[t] = 16.0f * vv[t] + pe;
    }
  }
  float sum = wave_sum64(vv[0] + vv[1] + vv[2] + vv[3]);
  float mu = sum * (1.0f / 256.0f);
  float d0 = vv[0]-mu, d1 = vv[1]-mu, d2 = vv[2]-mu, d3 = vv[3]-mu;
  float sq = wave_sum64(d0*d0 + d1*d1 + d2*d2 + d3*d3);
  float inv = 1.0f / (sqrtf(sq * (1.0f / 255.0f)) + 1e-6f);
  bf16 xo[4] = { __float2bfloat16(vv[0]), __float2bfloat16(vv[1]),
                 __float2bfloat16(vv[2]), __float2bfloat16(vv[3]) };
  *(uint2*)(x + (size_t)row * 256 + lane * 4) = *(uint2*)xo;
  float4 a4 = *(const float4*)(na + lane * 4);
  float4 b4 = *(const float4*)(nb + lane * 4);
  unsigned u = pack4_fp8(a4.x * d0 * inv + b4.x, a4.y * d1 * inv + b4.y,
                         a4.z * d2 * inv + b4.z, a4.w * d3 * inv + b4.w);
  *(unsigned*)(xn8 + (size_t)row * 256 + lane * 4) = u;
}

// LN2 over bf16 x -> fp8 xn8. one wave per row. grid 23040.
__global__ __launch_bounds__(256) void ln_k8(
    const bf16* __restrict__ x, const float* __restrict__ na,
    const float* __restrict__ nb, uchar* __restrict__ xn8)
{
  int row  = blockIdx.x * 4 + (threadIdx.x >> 6);
  int lane = threadIdx.x & 63;
  uint2 raw = *(const uint2*)(x + (size_t)row * 256 + lane * 4);
  bf16* xr = (bf16*)&raw;
  float v0 = __bfloat162float(xr[0]), v1 = __bfloat162float(xr[1]);
  float v2 = __bfloat162float(xr[2]), v3 = __bfloat162float(xr[3]);
  float sum = wave_sum64(v0 + v1 + v2 + v3);
  float mu = sum * (1.0f / 256.0f);
  float d0 = v0-mu, d1 = v1-mu, d2 = v2-mu, d3 = v3-mu;
  float sq = wave_sum64(d0*d0 + d1*d1 + d2*d2 + d3*d3);
  float inv = 1.0f / (sqrtf(sq * (1.0f / 255.0f)) + 1e-6f);
  float4 a4 = *(const float4*)(na + lane * 4);
  float4 b4 = *(const float4*)(nb + lane * 4);
  unsigned u = pack4_fp8(a4.x * d0 * inv + b4.x, a4.y * d1 * inv + b4.y,
                         a4.z * d2 * inv + b4.z, a4.w * d3 * inv + b4.w);
  *(unsigned*)(xn8 + (size_t)row * 256 + lane * 4) = u;
}

// ---------------------------------------------------------------------------
// K-resident fp8 GEMM (K=256 fixed): C = A[M][256] @ Bt[N][256]^T.
// 128x128 tile, full K in LDS (As+Bs=64KB), ONE barrier, 32x32x16 MFMA.
// R21 chunk swizzle: stored[row][p] = logical[row][(p&8)|((p&7)^(row&7))].
// MODE 3: bf16 residual in-place += acc (+bias) (swapped)
// MODE 4: QK (N=512): region n0>>8: 0 q8-layout, 1 k8-layout (swapped)
// MODE 5: V  (N=256): v^T8 layout [bh][64][360]  (unswapped)
// ---------------------------------------------------------------------------
template<int MODE>
__global__ __launch_bounds__(256) void gemm_k256(
    const uchar* __restrict__ A, const uchar* __restrict__ Bt,
    const float* __restrict__ bias,
    uchar* __restrict__ out8, bf16* __restrict__ xres,
    int N, int nTiles,
    const float* __restrict__ bq, const float* __restrict__ bk)
{
  __shared__ __align__(16) char smem[65536];   // As 32K | Bs 32K ; staging aliases
  uchar* As = (uchar*)smem;
  uchar* Bs = (uchar*)(smem + 32768);
  uchar* S8 = (uchar*)smem;                    // fp8 staging, stride 136, 128 rows
  bf16 (*Cs)[136] = (bf16 (*)[136])smem;       // bf16 staging (MODE3 halves)
  int chunk = gridDim.x >> 3;
  int bi = (blockIdx.x & 7) * chunk + (blockIdx.x >> 3);
  int m0 = (bi / nTiles) * 128, n0 = (bi % nTiles) * 128;
  int tid = threadIdx.x;
  int wave = tid >> 6, lane = tid & 63;
  int wm = (wave >> 1) * 64, wn = (wave & 1) * 64;
  int r32 = lane & 31, half = lane >> 5;

  // stage full K: coalesced (c = row*16 + p), XOR within the row.
  #pragma unroll
  for (int j = 0; j < 8; j++){
    int c = j * 256 + tid;
    int row = c >> 4, p = c & 15;
    int sl = (p & 8) | ((p & 7) ^ (row & 7));
    gl_lds16(A  + (size_t)(m0 + row) * 256 + sl * 16, As + (size_t)c * 16);
    gl_lds16(Bt + (size_t)(n0 + row) * 256 + sl * 16, Bs + (size_t)c * 16);
  }

  f32x16 acc[2][2];
  #pragma unroll
  for (int mb = 0; mb < 2; mb++)
    #pragma unroll
    for (int nb = 0; nb < 2; nb++)
      #pragma unroll
      for (int e = 0; e < 16; e++) acc[mb][nb][e] = 0.f;

  __syncthreads();   // single barrier: all 64KB staged

  #pragma unroll
  for (int c = 0; c < 8; c++){
    int l0 = 2 * c + half;                       // logical 16B chunk
    i64 alo[2], ahi[2], blo[2], bhi[2];
    #pragma unroll
    for (int mb = 0; mb < 2; mb++){
      int row = wm + mb * 32 + r32;
      int st = (l0 & 8) | ((l0 & 7) ^ (row & 7));
      uint4 v = *(const uint4*)(As + row * 256 + st * 16);
      alo[mb] = *(const i64*)&v.x;  ahi[mb] = *(const i64*)&v.z;
    }
    #pragma unroll
    for (int nb = 0; nb < 2; nb++){
      int row = wn + nb * 32 + r32;
      int st = (l0 & 8) | ((l0 & 7) ^ (row & 7));
      uint4 v = *(const uint4*)(Bs + row * 256 + st * 16);
      blo[nb] = *(const i64*)&v.x;  bhi[nb] = *(const i64*)&v.z;
    }
    #pragma unroll
    for (int mb = 0; mb < 2; mb++)
      #pragma unroll
      for (int nb = 0; nb < 2; nb++){
        if (MODE == 5){
          acc[mb][nb] = __builtin_amdgcn_mfma_f32_32x32x16_fp8_fp8(alo[mb], blo[nb], acc[mb][nb], 0, 0, 0);
          acc[mb][nb] = __builtin_amdgcn_mfma_f32_32x32x16_fp8_fp8(ahi[mb], bhi[nb], acc[mb][nb], 0, 0, 0);
        } else {   // swapped: D rows = n, cols = m
          acc[mb][nb] = __builtin_amdgcn_mfma_f32_32x32x16_fp8_fp8(blo[nb], alo[mb], acc[mb][nb], 0, 0, 0);
          acc[mb][nb] = __builtin_amdgcn_mfma_f32_32x32x16_fp8_fp8(bhi[nb], ahi[mb], acc[mb][nb], 0, 0, 0);
        }
      }
  }

  __syncthreads();   // As/Bs dead; staging aliases

  // 32x32 D layout: "col" = lane&31, "row" = (reg&3) + 8*(reg>>2) + 4*half.
  if (MODE == 4){
    const int region = n0 >> 8;
    const float* bb = (region == 0 ? bq : bk);
    // swapped: m = lane&31 (fixed), reg-quad g = 4 consecutive n. Staging [m][n].
    #pragma unroll
    for (int mb = 0; mb < 2; mb++){
      int m_l = wm + mb * 32 + r32;
      #pragma unroll
      for (int nb = 0; nb < 2; nb++)
        #pragma unroll
        for (int g = 0; g < 4; g++){
          int n_l = wn + nb * 32 + g * 8 + half * 4;
          int bidx = (n0 & 255) + n_l;
          float v0 = acc[mb][nb][g * 4 + 0] + bb[bidx + 0];
          float v1 = acc[mb][nb][g * 4 + 1] + bb[bidx + 1];
          float v2 = acc[mb][nb][g * 4 + 2] + bb[bidx + 2];
          float v3 = acc[mb][nb][g * 4 + 3] + bb[bidx + 3];
          *(unsigned*)(S8 + m_l * 136 + n_l) = pack4_fp8(v0, v1, v2, v3);
        }
    }
    __syncthreads();
    int lr = tid >> 1, seg = tid & 1;
    #pragma unroll
    for (int j = 0; j < 4; j++){
      int nl = seg * 64 + j * 16;
      uint2 a = *(uint2*)(S8 + lr * 136 + nl);
      uint2 b = *(uint2*)(S8 + lr * 136 + nl + 8);
      uint4 st = make_uint4(a.x, a.y, b.x, b.y);
      int m = m0 + lr;
      int b_ = m / 360, s = m - b_ * 360;
      int nnl = (n0 & 255) + nl;
      int h = nnl >> 6, dk = nnl & 63;
      size_t roff = (region == 1) ? 23592960ull : 0ull;
      *(uint4*)(out8 + roff + ((size_t)(b_ * 4 + h) * 360 + s) * 64 + dk) = st;
    }
  } else if (MODE == 5){
    // unswapped: n = lane&31 (fixed), reg-quad g = 4 consecutive m. Staging [n][m].
    #pragma unroll
    for (int nb = 0; nb < 2; nb++){
      int n_l = wn + nb * 32 + r32;
      float bv_ = bias[n0 + n_l];
      #pragma unroll
      for (int mb = 0; mb < 2; mb++)
        #pragma unroll
        for (int g = 0; g < 4; g++){
          int m_l = wm + mb * 32 + g * 8 + half * 4;
          *(unsigned*)(S8 + n_l * 136 + m_l) =
              pack4_fp8(acc[mb][nb][g * 4 + 0] + bv_, acc[mb][nb][g * 4 + 1] + bv_,
                        acc[mb][nb][g * 4 + 2] + bv_, acc[mb][nb][g * 4 + 3] + bv_);
        }
    }
    __syncthreads();
    int nn = tid >> 1, part = tid & 1;
    int nnl = n0 + nn;                    // N=256
    int h = nnl >> 6, dk = nnl & 63;
    #pragma unroll
    for (int j0 = 0; j0 < 64; j0 += 8){
      int mm = m0 + part * 64 + j0;       // 8-aligned; 360%8==0 -> no batch cross
      int b_ = mm / 360, s = mm - b_ * 360;
      uint2 val = *(uint2*)(S8 + nn * 136 + part * 64 + j0);
      *(uint2*)(out8 + ((size_t)((b_ * 4 + h) * 64 + dk)) * 360 + s) = val;
    }
  } else {  // MODE 3: bf16 residual, halves, swapped orientation
    #pragma unroll
    for (int hb = 0; hb < 2; hb++){
      if ((wave >> 1) == hb){
        #pragma unroll
        for (int mb = 0; mb < 2; mb++){
          int ml = mb * 32 + r32;               // local to half
          #pragma unroll
          for (int nb = 0; nb < 2; nb++)
            #pragma unroll
            for (int g = 0; g < 4; g++){
              int nl0 = wn + nb * 32 + g * 8 + half * 4;
              float v0 = acc[mb][nb][g * 4 + 0] + bias[n0 + nl0 + 0];
              float v1 = acc[mb][nb][g * 4 + 1] + bias[n0 + nl0 + 1];
              float v2 = acc[mb][nb][g * 4 + 2] + bias[n0 + nl0 + 2];
              float v3 = acc[mb][nb][g * 4 + 3] + bias[n0 + nl0 + 3];
              *(unsigned*)(&Cs[ml][nl0])     = pack2(v0, v1);
              *(unsigned*)(&Cs[ml][nl0 + 2]) = pack2(v2, v3);
            }
        }
      }
      __syncthreads();
      int mbase = m0 + hb * 64;
      int lr = tid >> 2, seg = tid & 3;
      bf16* op = xres + (size_t)(mbase + lr) * 256 + n0 + seg * 32;
      #pragma unroll
      for (int j = 0; j < 4; j++){
        uint4 cv = *(uint4*)(&Cs[lr][seg * 32 + j * 8]);
        uint4 xv = *(uint4*)(op + j * 8);
        bf16* ca = (bf16*)&cv; bf16* xa = (bf16*)&xv;
        bf16 o8[8];
        #pragma unroll
        for (int t = 0; t < 8; t++)
          o8[t] = __float2bfloat16(__bfloat162float(ca[t]) + __bfloat162float(xa[t]));
        *(uint4*)(op + j * 8) = *(uint4*)o8;
      }
      __syncthreads();
    }
  }
}

// ---------------------------------------------------------------------------
// Fused FFN (R21 structure), pipelined, A-in-registers.
// x += (relu(xn8 @ W1 + b1) @ W2 + b2). 720 blocks x 512 thr. LDS 160KiB:
// A 32K @0 (read ONCE into 64 VGPR/lane) | W1 dbuf 2x32K @32768 |
// W2 dbuf 2x32K @98304. 3-bit XOR chunk swizzles. Per slab (128 hid):
//   FFN1 (regs x W1[cur]) -> barrier_lgkm -> prefetch s+1 -> h over W1[cur]
//   -> barrier_lgkm -> FFN2 -> __syncthreads (vmcnt drain).
// Epilogue: collision-free Cs stride 264 (67.6KB in dead W region).
// ---------------------------------------------------------------------------
__global__ __launch_bounds__(512) void gemm_ffn(
    const uchar* __restrict__ A, const uchar* __restrict__ W1t,
    const uchar* __restrict__ W2t, const float* __restrict__ b1,
    const float* __restrict__ b2, bf16* __restrict__ xres)
{
  extern __shared__ __align__(16) char sm[];
  const int W1OFF = 32768, W2OFF = 98304;      // + buf*32768
  int bi = (blockIdx.x & 7) * 90 + (blockIdx.x >> 3);   // 720 = 8*90
  int m0 = bi * 128;
  int tid = threadIdx.x;
  int wave = tid >> 6, lane = tid & 63;
  int wm = (wave & 1) * 64, wn = (wave >> 1) * 64;      // FFN2: 2m x 4n
  int wnh = (wave >> 1) * 32;                           // FFN1: 2m x 4h(32)
  int r32 = lane & 31, half = lane >> 5;

  // stage A tile once: coalesced, c = row*16 + p, XOR within row.
  #pragma unroll
  for (int j = 0; j < 4; j++){
    int c = j * 512 + tid;
    int row = c >> 4, p = c & 15;
    int sl = (p & 8) | ((p & 7) ^ (row & 7));
    gl_lds16(A + (size_t)(m0 + row) * 256 + sl * 16, sm + c * 16);
  }
  // stage W slab 0 into buf 0.
  #pragma unroll
  for (int j = 0; j < 4; j++){
    int c = j * 512 + tid;
    int row1 = c >> 4, p1 = c & 15;
    int sl1 = (p1 & 8) | ((p1 & 7) ^ (row1 & 7));
    gl_lds16(W1t + (size_t)row1 * 256 + sl1 * 16, sm + W1OFF + c * 16);
    int row2 = c >> 3, p2 = c & 7;
    int sl2 = p2 ^ (row2 & 7);
    gl_lds16(W2t + (size_t)row2 * 2048 + sl2 * 16, sm + W2OFF + c * 16);
  }

  f32x16 acc2[2][2];
  #pragma unroll
  for (int mb = 0; mb < 2; mb++)
    #pragma unroll
    for (int nb = 0; nb < 2; nb++)
      #pragma unroll
      for (int e = 0; e < 16; e++) acc2[mb][nb][e] = 0.f;

  __syncthreads();

  // hoist A fragments to registers (once; eliminates 128KB/slab LDS reads)
  i64 Alo[2][8], Ahi[2][8];
  #pragma unroll
  for (int c = 0; c < 8; c++){
    int l0 = 2 * c + half;
    #pragma unroll
    for (int mb = 0; mb < 2; mb++){
      int row = wm + mb * 32 + r32;
      int st = (l0 & 8) | ((l0 & 7) ^ (row & 7));
      uint4 v = *(const uint4*)(sm + row * 256 + st * 16);
      Alo[mb][c] = *(const i64*)&v.x;  Ahi[mb][c] = *(const i64*)&v.z;
    }
  }

  int cur = 0;
  for (int s = 0; s < 16; s++){
    const int w1o = W1OFF + cur * 32768;
    const int w2o = W2OFF + cur * 32768;

    // FFN1: acc1 = A(regs) @ W1_slab^T (swapped: D rows = hidden, cols = m)
    f32x16 acc1[2];
    #pragma unroll
    for (int mb = 0; mb < 2; mb++)
      #pragma unroll
      for (int e = 0; e < 16; e++) acc1[mb][e] = 0.f;
    #pragma unroll
    for (int c = 0; c < 8; c++){
      int l0 = 2 * c + half;
      int roww = wnh + r32;
      int stw = (l0 & 8) | ((l0 & 7) ^ (roww & 7));
      uint4 w = *(const uint4*)(sm + w1o + roww * 256 + stw * 16);
      i64 wlo = *(const i64*)&w.x, whi = *(const i64*)&w.z;
      #pragma unroll
      for (int mb = 0; mb < 2; mb++){
        acc1[mb] = __builtin_amdgcn_mfma_f32_32x32x16_fp8_fp8(wlo, Alo[mb][c], acc1[mb], 0, 0, 0);
        acc1[mb] = __builtin_amdgcn_mfma_f32_32x32x16_fp8_fp8(whi, Ahi[mb][c], acc1[mb], 0, 0, 0);
      }
    }
    barrier_lgkm();     // all waves done reading W1[cur]; vmcnt NOT drained

    // prefetch slab s+1 into buf^1 (in flight across the lgkm barriers)
    if (s < 15){
      int nxt = cur ^ 1;
      #pragma unroll
      for (int j = 0; j < 4; j++){
        int c = j * 512 + tid;
        int row1 = c >> 4, p1 = c & 15;
        int sl1 = (p1 & 8) | ((p1 & 7) ^ (row1 & 7));
        gl_lds16(W1t + (size_t)((s + 1) * 128 + row1) * 256 + sl1 * 16,
                 sm + W1OFF + nxt * 32768 + c * 16);
        int row2 = c >> 3, p2 = c & 7;
        int sl2 = p2 ^ (row2 & 7);
        gl_lds16(W2t + (size_t)row2 * 2048 + (s + 1) * 128 + sl2 * 16,
                 sm + W2OFF + nxt * 32768 + c * 16);
      }
    }

    // h = relu(acc1 + b1) -> fp8 over W1[cur] region: [128 m][128 hid], XOR
    #pragma unroll
    for (int mb = 0; mb < 2; mb++){
      int m = wm + mb * 32 + r32;
      #pragma unroll
      for (int g = 0; g < 4; g++){
        int n_l = wnh + g * 8 + half * 4;
        float4 bv = *(const float4*)(b1 + s * 128 + n_l);
        float v0 = fmaxf(acc1[mb][g * 4 + 0] + bv.x, 0.f);
        float v1 = fmaxf(acc1[mb][g * 4 + 1] + bv.y, 0.f);
        float v2 = fmaxf(acc1[mb][g * 4 + 2] + bv.z, 0.f);
        float v3 = fmaxf(acc1[mb][g * 4 + 3] + bv.w, 0.f);
        int sl = (n_l >> 4) ^ (m & 7);
        *(unsigned*)(sm + w1o + m * 128 + sl * 16 + (n_l & 15)) =
            pack4_fp8(v0, v1, v2, v3);
      }
    }
    barrier_lgkm();     // h visible; prefetch still in flight

    // FFN2: acc2 += h @ W2_slab (swapped: D rows = out-col, cols = m)
    #pragma unroll
    for (int c = 0; c < 4; c++){
      int l0 = 2 * c + half;
      i64 hlo[2], hhi[2], wlo[2], whi[2];
      #pragma unroll
      for (int mb = 0; mb < 2; mb++){
        int row = wm + mb * 32 + r32;
        int st = l0 ^ (row & 7);
        uint4 v = *(const uint4*)(sm + w1o + row * 128 + st * 16);
        hlo[mb] = *(const i64*)&v.x;  hhi[mb] = *(const i64*)&v.z;
      }
      #pragma unroll
      for (int nb = 0; nb < 2; nb++){
        int row = wn + nb * 32 + r32;
        int st = l0 ^ (row & 7);
        uint4 v = *(const uint4*)(sm + w2o + row * 128 + st * 16);
        wlo[nb] = *(const i64*)&v.x;  whi[nb] = *(const i64*)&v.z;
      }
      #pragma unroll
      for (int mb = 0; mb < 2; mb++)
        #pragma unroll
        for (int nb = 0; nb < 2; nb++){
          acc2[mb][nb] = __builtin_amdgcn_mfma_f32_32x32x16_fp8_fp8(wlo[nb], hlo[mb], acc2[mb][nb], 0, 0, 0);
          acc2[mb][nb] = __builtin_amdgcn_mfma_f32_32x32x16_fp8_fp8(whi[nb], hhi[mb], acc2[mb][nb], 0, 0, 0);
        }
    }
    __syncthreads();    // drains vmcnt: buf^1 ready; h/W2[cur] dead
    cur ^= 1;
  }

  // epilogue: acc2 + b2 -> bf16 Cs [128][264] (collision-free), RMW x.
  bf16 (*Cs)[264] = (bf16 (*)[264])(sm + W1OFF);
  #pragma unroll
  for (int mb = 0; mb < 2; mb++){
    int ml = wm + mb * 32 + r32;
    #pragma unroll
    for (int nb = 0; nb < 2; nb++)
      #pragma unroll
      for (int g = 0; g < 4; g++){
        int nl0 = wn + nb * 32 + g * 8 + half * 4;
        float4 bv = *(const float4*)(b2 + nl0);
        float v0 = acc2[mb][nb][g * 4 + 0] + bv.x;
        float v1 = acc2[mb][nb][g * 4 + 1] + bv.y;
        float v2 = acc2[mb][nb][g * 4 + 2] + bv.z;
        float v3 = acc2[mb][nb][g * 4 + 3] + bv.w;
        *(unsigned*)(&Cs[ml][nl0])     = pack2(v0, v1);
        *(unsigned*)(&Cs[ml][nl0 + 2]) = pack2(v2, v3);
      }
  }
  __syncthreads();
  int lr = tid >> 2, seg = tid & 3;
  bf16* op = xres + (size_t)(m0 + lr) * 256 + seg * 64;
  #pragma unroll
  for (int j = 0; j < 8; j++){
    uint4 cv = *(uint4*)(&Cs[lr][seg * 64 + j * 8]);
    uint4 xv = *(uint4*)(op + j * 8);
    bf16* ca = (bf16*)&cv; bf16* xa = (bf16*)&xv;
    bf16 o8[8];
    #pragma unroll
    for (int t = 0; t < 8; t++)
      o8[t] = __float2bfloat16(__bfloat162float(ca[t]) + __bfloat162float(xa[t]));
    *(uint4*)(op + j * 8) = *(uint4*)o8;
  }
}

// attn5 kc-step. TAIL=true only for kc=11 (keys 352..383): row clamps +
// key<360 zeroing live only there (p1 is compile-time dead in tail).
template<bool TAIL>
static __device__ __forceinline__ void attn_step(
    int kc, const uchar (*Ks)[80], uchar (*Pb)[16][48],
    const uchar* __restrict__ vb, int wave, int r, int qd,
    const i64* qa0, const i64* qa1, float* lsum, f32x4 (*accO)[4])
{
  int krow0 = kc * 32 + r;
  int krow1 = krow0 + 16;
  if (TAIL){ if (krow0 > 359) krow0 = 359; if (krow1 > 359) krow1 = 359; }
  i64 kf00 = *(const i64*)(&Ks[krow0][qd * 8]);
  i64 kf01 = *(const i64*)(&Ks[krow0][32 + qd * 8]);
  i64 kf10 = *(const i64*)(&Ks[krow1][qd * 8]);
  i64 kf11 = *(const i64*)(&Ks[krow1][32 + qd * 8]);
  i64 vf[4];
  #pragma unroll
  for (int dt = 0; dt < 4; dt++)
    vf[dt] = *(const i64*)(vb + (size_t)(dt * 16 + r) * 360 + kc * 32 + qd * 8);

  const float CEXP = 0.18033688011112042f;   // 0.125 * log2(e)

  #pragma unroll
  for (int tl = 0; tl < 3; tl++){
    f32x4 z0 = {0.f, 0.f, 0.f, 0.f}, z1 = {0.f, 0.f, 0.f, 0.f};
    z0 = __builtin_amdgcn_mfma_f32_16x16x32_fp8_fp8(kf00, qa0[tl], z0, 0, 0, 0);
    z0 = __builtin_amdgcn_mfma_f32_16x16x32_fp8_fp8(kf01, qa1[tl], z0, 0, 0, 0);
    z1 = __builtin_amdgcn_mfma_f32_16x16x32_fp8_fp8(kf10, qa0[tl], z1, 0, 0, 0);
    z1 = __builtin_amdgcn_mfma_f32_16x16x32_fp8_fp8(kf11, qa1[tl], z1, 0, 0, 0);
    float p0[4], p1[4];
    #pragma unroll
    for (int i = 0; i < 4; i++){
      p0[i] = fexp2(z0[i] * CEXP);
      p1[i] = fexp2(z1[i] * CEXP);
      if (TAIL){
        if (kc * 32 + qd * 4 + i >= 360) p0[i] = 0.f;
        if (kc * 32 + 16 + qd * 4 + i >= 360) p1[i] = 0.f;
      }
      lsum[tl] += p0[i] + p1[i];
    }
    *(unsigned*)(&Pb[wave][r][qd * 4])      = pack4_fp8(p0[0], p0[1], p0[2], p0[3]);
    *(unsigned*)(&Pb[wave][r][16 + qd * 4]) = pack4_fp8(p1[0], p1[1], p1[2], p1[3]);
    asm volatile("s_waitcnt lgkmcnt(0)" ::: "memory");
    i64 pa = *(const i64*)(&Pb[wave][r][qd * 8]);
    // swapped PV: D[d_local=qd*4+i][q=r] -> lane holds 4 consecutive d at q=r
    #pragma unroll
    for (int dt = 0; dt < 4; dt++)
      accO[tl][dt] = __builtin_amdgcn_mfma_f32_16x16x32_fp8_fp8(pa, vf[dt], accO[tl][dt], 0, 0, 0);
    asm volatile("s_waitcnt lgkmcnt(0)" ::: "memory");
  }
}

// attn5: fp8 flash attention. one block per (b,h) [1024], 512 thr / 8 waves,
// 3 q-tiles/wave, single-pass softmax (pad queries: Q zeroed -> uniform).
__global__ __launch_bounds__(512) void attn5(
    const uchar* __restrict__ q, const uchar* __restrict__ kk, const uchar* __restrict__ vt,
    const int* __restrict__ src, uchar* __restrict__ ctx8)
{
  __shared__ __align__(16) uchar smem[34944];            // Ks 28800 | Pb 6144
  uchar (*Ks)[80]     = (uchar (*)[80])smem;             // [360][80]
  uchar (*Pb)[16][48] = (uchar (*)[16][48])(smem + 28800); // [8][16][48]
  int bh = blockIdx.x;
  int b = bh >> 2, h = bh & 3;
  int wave = threadIdx.x >> 6, lane = threadIdx.x & 63;
  int r = lane & 15, qd = lane >> 4;
  const uchar* qb = q  + (size_t)bh * 360 * 64;
  const uchar* kb = kk + (size_t)bh * 360 * 64;
  const uchar* vb = vt + (size_t)bh * 64 * 360;
  const int* srow = src + b * 360;

  for (int c = threadIdx.x; c < 1440; c += 512){
    int row = c >> 2, g = c & 3;
    *(uint4*)(&Ks[row][g * 16]) = *(const uint4*)(kb + row * 64 + g * 16);
  }
  __syncthreads();

  i64 qa0[3], qa1[3];
  float lsum[3];
  f32x4 accO[3][4];
  #pragma unroll
  for (int tl = 0; tl < 3; tl++){
    int qt = wave * 3 + tl;
    int qg = qt * 16 + r;
    int qrow = qg > 359 ? 359 : qg;
    bool qp = (qg < 360) && (srow[qg] == 799);
    i64 a0 = *(const i64*)(qb + qrow * 64 + qd * 8);
    i64 a1 = *(const i64*)(qb + qrow * 64 + 32 + qd * 8);
    qa0[tl] = qp ? 0 : a0;          // pad query: Q=0 -> z=0 -> p=1 (uniform)
    qa1[tl] = qp ? 0 : a1;
    lsum[tl] = 0.f;
    #pragma unroll
    for (int dt = 0; dt < 4; dt++) accO[tl][dt] = (f32x4){0.f, 0.f, 0.f, 0.f};
  }

  for (int kc = 0; kc < 11; kc++)
    attn_step<false>(kc, Ks, Pb, vb, wave, r, qd, qa0, qa1, lsum, accO);
  attn_step<true>(11, Ks, Pb, vb, wave, r, qd, qa0, qa1, lsum, accO);

  __syncthreads();                  // all waves past Ks reads; Cb aliases Ks
  uchar* Cw = smem + wave * 1280;   // per-wave [16][80] staging over dead Ks

  #pragma unroll
  for (int tl = 0; tl < 3; tl++){
    float ls = lsum[tl];
    ls += __shfl_xor(ls, 16, 64);
    ls += __shfl_xor(ls, 32, 64);
    float invl = 1.0f / ls;         // lane-local: accO cols are own q=r
    #pragma unroll
    for (int dt = 0; dt < 4; dt++)
      *(unsigned*)(Cw + r * 80 + dt * 16 + qd * 4) =
          pack4_fp8(accO[tl][dt][0] * invl, accO[tl][dt][1] * invl,
                    accO[tl][dt][2] * invl, accO[tl][dt][3] * invl);
    asm volatile("s_waitcnt lgkmcnt(0)" ::: "memory");
    int qt = wave * 3 + tl;
    int qglob = qt * 16 + r;
    if (qglob < 360)
      *(uint4*)(ctx8 + ((size_t)(b * 360 + qglob)) * 256 + h * 64 + qd * 16) =
          *(uint4*)(Cw + r * 80 + qd * 16);
    asm volatile("s_waitcnt lgkmcnt(0)" ::: "memory");
  }
}

// head: one block per batch (grid 256, 4 waves).
__global__ __launch_bounds__(256) void head_k(
    const bf16* __restrict__ x, const int* __restrict__ src,
    const float* __restrict__ wl, const float* __restrict__ bl,
    float* __restrict__ out)
{
  __shared__ bf16 Xs[192][264];
  int b = blockIdx.x;
  int tid = threadIdx.x;
  int wave = tid >> 6, lane = tid & 63;
  int g = lane >> 3, sub = lane & 7;

  const bf16* xb = x + (size_t)b * 360 * 256;
  for (int it = 0; it < 24; it++){
    int idx = tid + it * 256;
    int row = idx >> 5, col = idx & 31;
    *(uint4*)(&Xs[row][col * 8]) = *(const uint4*)(xb + row * 256 + col * 8);
  }

  float wv[96];
  {
    const float4* wr4 = (const float4*)(wl + (size_t)(g * 256 + sub * 32) * 3);
    #pragma unroll
    for (int c = 0; c < 24; c++) *(float4*)(&wv[c * 4]) = wr4[c];
  }
  float bl0 = bl[0], bl1 = bl[1], bl2 = bl[2];
  const int* sr = src + b * 360;
  __syncthreads();

  for (int p = wave; p < 91; p += 4){
    int i = 0, rem = p;
    while (rem >= 13 - i){ rem -= 13 - i; i++; }
    int j = i + 1 + rem;
    int base = 12 * i - (i * (i - 1)) / 2;
    int pe = base + (j - i) - 1;
    int eb = 28 + 2 * pe;

    int idxg;
    if (g == 0) idxg = 2 * i;
    else if (g == 1) idxg = 2 * i + 1;
    else if (g == 2) idxg = 2 * j;
    else if (g == 3) idxg = 2 * j + 1;
    else idxg = eb + (g - 4);
    bool zm = !(g >= 4 && j == 13);

    uint4 xv[4];
    #pragma unroll
    for (int c = 0; c < 4; c++) xv[c] = *(uint4*)(&Xs[idxg][sub * 32 + c * 8]);
    const bf16* xa = (const bf16*)xv;
    float a0 = 0.f, a1 = 0.f, a2 = 0.f;
    #pragma unroll
    for (int t = 0; t < 32; t++){
      float f = zm ? __bfloat162float(xa[t]) : 0.0f;
      a0 += f * wv[t * 3 + 0];
      a1 += f * wv[t * 3 + 1];
      a2 += f * wv[t * 3 + 2];
    }
    #pragma unroll
    for (int o = 1; o < 64; o <<= 1){
      a0 += __shfl_xor(a0, o, 64);
      a1 += __shfl_xor(a1, o, 64);
      a2 += __shfl_xor(a2, o, 64);
    }
    if (lane == 0){
      int ti = sr[2 * i], ai = sr[2 * i + 1], tj = sr[2 * j], aj = sr[2 * j + 1];
      bool c1 = (ai == 2) || (aj == 2);
      bool c2 = (tj == 1) || (ai == 1) || (aj == 1);
      bool c3 = (ti == 799) || (tj == 799) || (ai == 0) || (aj == 0);
      bool c4 = false;
      if (j < 13){
        int es = 28 + 4 * pe;
        c4 = (sr[es] == 1) || (sr[es + 1] == 1) || (sr[es + 2] == 1) || (sr[es + 3] == 1);
      }
      bool m1 = c3 || c4, m2 = m1 || c2, m3 = m2 || c1;
      float* op = out + ((size_t)b * 91 + p) * 3;
      op[0] = m1 ? -1.0e9f : (a0 + bl0);
      op[1] = m2 ? -1.0e9f : (a1 + bl1);
      op[2] = m3 ? -1.0e9f : (a2 + bl2);
    }
  }
}

extern "C" void kernel_launch(void* const* d_in, const int* in_sizes, int n_in,
                              void* d_out, int out_size, void* d_ws, size_t ws_size,
                              hipStream_t stream)
{
  const int*   src = (const int*)  d_in[0];
  const float* emb = (const float*)d_in[1];
  const float* wq  = (const float*)d_in[2];  const float* bq = (const float*)d_in[3];
  const float* wk  = (const float*)d_in[4];  const float* bk = (const float*)d_in[5];
  const float* wv  = (const float*)d_in[6];  const float* bv = (const float*)d_in[7];
  const float* wo  = (const float*)d_in[8];  const float* bo = (const float*)d_in[9];
  const float* n1a = (const float*)d_in[10]; const float* n1b = (const float*)d_in[11];
  const float* n2a = (const float*)d_in[12]; const float* n2b = (const float*)d_in[13];
  const float* w1  = (const float*)d_in[14]; const float* b1 = (const float*)d_in[15];
  const float* w2  = (const float*)d_in[16]; const float* b2 = (const float*)d_in[17];
  const float* wl  = (const float*)d_in[18]; const float* bl = (const float*)d_in[19];
  float* out = (float*)d_out;

  if (ws_size < 191365120ull) return;

  char* ws = (char*)d_ws;
  bf16*  x    = (bf16*)(ws);                   // [92160][256] bf16
  uchar* xn8  = (uchar*)(ws + 47185920ull);    // [92160][256] fp8: LN1 / ctx8 / LN2
  char*  R    = ws + 70778880ull;
  uchar* q8   = (uchar*)(R);                   // [1024][360][64]; k8 +23592960
  uchar* vt8  = (uchar*)(R + 47185920ull);     // [1024][64][360]
  char*  wC   = ws + 165150720ull;             // weights at workspace tail
  uchar* wqkv8 = (uchar*)(wC);                 // [768][256] fp8
  uchar* wo8   = (uchar*)(wC + 196608);        // [256][256] fp8
  uchar* w1f8T = (uchar*)(wC + 262144);        // [2048][256] fp8
  uchar* w2f8T = (uchar*)(wC + 786432);        // [256][2048] fp8  (end 166461440)

  cvt_all<<<1280, 256, 0, stream>>>(wq, wk, wv, wo, w1, w2,
                                    wqkv8, wqkv8 + 65536, wqkv8 + 131072,
                                    wo8, w1f8T, w2f8T);

  embed_ln1<<<23040, 256, 0, stream>>>(src, emb, n1a, n1b, x, xn8);

  // QK: N=512 (rows 0..511 of wqkv8), 720x4 = 2880 blocks.
  gemm_k256<4><<<2880, 256, 0, stream>>>(xn8, wqkv8, nullptr, q8, nullptr,
                                         512, 4, bq, bk);
  // V: N=256 (rows 512..767), MODE5 -> vt8. 720x2 = 1440 blocks.
  gemm_k256<5><<<1440, 256, 0, stream>>>(xn8, wqkv8 + 131072, bv, vt8, nullptr,
                                         256, 2, nullptr, nullptr);

  attn5<<<1024, 512, 0, stream>>>(q8, q8 + 23592960ull, vt8, src, xn8 /* ctx8 */);

  gemm_k256<3><<<1440, 256, 0, stream>>>(xn8, wo8, bo, nullptr, x,
                                         256, 2, nullptr, nullptr);

  ln_k8<<<23040, 256, 0, stream>>>(x, n2a, n2b, xn8);

  // fused FFN (R21 structure): 720 blocks x 512 thr, 160KiB dynamic LDS.
  gemm_ffn<<<720, 512, 163840, stream>>>(xn8, w1f8T, w2f8T, b1, b2, x);

  head_k<<<256, 256, 0, stream>>>(x, src, wl, bl, out);
}